// Round 7
// baseline (615.632 us; speedup 1.0000x reference)
//
#include <hip/hip_runtime.h>
#include <math.h>

#define Bsz 1024
#define Tt  128
#define Ff  32
#define Ee  16
#define Hh  20
#define Dd  4096
#define EPSc 1e-3f

// repacked fp32 weights per expert, gate-interleaved cols c = 4*u + g (g: i,f,g,o):
// K1p[32][80]@0, R1p[20][80]@2560, K2p[20][80]@4160, R2p[20][80]@5760,
// b1p[80]@7360, b2p[80]@7440  -> 7520 floats per expert
#define PWE 7520

typedef __attribute__((ext_vector_type(8))) short bf16x8;
typedef __attribute__((ext_vector_type(4))) float f32x4;

#define MFMA16(a,b,c) __builtin_amdgcn_mfma_f32_16x16x32_bf16(a, b, c, 0, 0, 0)

__device__ __forceinline__ float sigmoidf_(float x) {
    return 1.0f / (1.0f + __expf(-x));
}
__device__ __forceinline__ unsigned short bf16_rne(float f) {
    unsigned u = __float_as_uint(f);
    u += 0x7FFFu + ((u >> 16) & 1u);
    return (unsigned short)(u >> 16);
}
__device__ __forceinline__ float bf16_to_f(unsigned short h) {
    return __uint_as_float(((unsigned)h) << 16);
}
// truncation split: f = hi + lo with hi = trunc16(f); dropped lo*lo term <= 2^-16 rel
__device__ __forceinline__ void split8(const float* v, bf16x8& hv, bf16x8& lv) {
#pragma unroll
    for (int j = 0; j < 8; ++j) {
        unsigned u = __float_as_uint(v[j]);
        hv[j] = (short)(unsigned short)(u >> 16);
        float hf = __uint_as_float(u & 0xFFFF0000u);
        lv[j] = (short)bf16_rne(v[j] - hf);
    }
}

// ---------------------------------------------------------------- x prepass: BN + bf16 hi/lo split
// into per-(chunk,t,lane) A-fragment layout: elem (c,t,l)*8  holds xn[c*16+s][t][q*8..+8]
__global__ void xpack_kernel(const float* __restrict__ x,
                             const float* __restrict__ gamma, const float* __restrict__ beta,
                             const float* __restrict__ mean,  const float* __restrict__ var,
                             unsigned short* __restrict__ xph, unsigned short* __restrict__ xpl)
{
    __shared__ float sc[Ff], sh[Ff];
    int tid = threadIdx.x;
    if (tid < Ff) {
        float s = gamma[tid] * rsqrtf(var[tid] + EPSc);
        sc[tid] = s;
        sh[tid] = beta[tid] - mean[tid] * s;
    }
    __syncthreads();
    int idx = blockIdx.x * 256 + tid;           // 0 .. 64*128*64-1
    int c   = idx >> 13;
    int rem = idx & 8191;
    int t   = rem >> 6;
    int l   = rem & 63;
    int q   = l >> 4, s = l & 15;
    const float* xr = x + ((size_t)(c * 16 + s) * Tt + t) * Ff + q * 8;
    float4 v0 = *(const float4*)xr;
    float4 v1 = *(const float4*)(xr + 4);
    float xv[8] = {v0.x, v0.y, v0.z, v0.w, v1.x, v1.y, v1.z, v1.w};
    bf16x8 hv, lv;
#pragma unroll
    for (int j = 0; j < 8; ++j) {
        int f = q * 8 + j;
        float xn_ = xv[j] * sc[f] + sh[f];
        unsigned short hi = bf16_rne(xn_);
        hv[j] = (short)hi;
        lv[j] = (short)bf16_rne(xn_ - bf16_to_f(hi));
    }
    *(bf16x8*)(xph + (size_t)idx * 8) = hv;
    *(bf16x8*)(xpl + (size_t)idx * 8) = lv;
}

// ---------------------------------------------------------------- weight repack (gate-interleave)
__global__ void repack2_kernel(const float* __restrict__ k1, const float* __restrict__ r1,
                               const float* __restrict__ b1, const float* __restrict__ k2,
                               const float* __restrict__ r2, const float* __restrict__ b2,
                               float* __restrict__ pw)
{
    int idx = blockIdx.x * blockDim.x + threadIdx.x;
    if (idx >= Ee * PWE) return;
    int e = idx / PWE;
    int o = idx % PWE;
    float v;
    if (o < 7360) {
        int c = o % 80, u = c >> 2, g = c & 3;
        int co = g * 20 + u;
        if (o < 2560) {
            int kk = o / 80;
            v = k1[((size_t)e * Ff + kk) * 80 + co];
        } else if (o < 4160) {
            int kk = (o - 2560) / 80;
            v = r1[((size_t)e * Hh + kk) * 80 + co];
        } else if (o < 5760) {
            int kk = (o - 4160) / 80;
            v = k2[((size_t)e * Hh + kk) * 80 + co];
        } else {
            int kk = (o - 5760) / 80;
            v = r2[((size_t)e * Hh + kk) * 80 + co];
        }
    } else if (o < 7440) {
        int c = o - 7360, u = c >> 2, g = c & 3;
        v = b1[(size_t)e * 80 + g * 20 + u];
    } else {
        int c = o - 7440, u = c >> 2, g = c & 3;
        v = b2[(size_t)e * 80 + g * 20 + u];
    }
    pw[idx] = v;
}

// ---------------------------------------------------------------- fused lstm + fc1, per-SIMD co-residency
// 512 blocks x 256 thr, __launch_bounds__(256,2) -> 2 blocks/CU -> every SIMD
// hosts exactly 1 lstm wave + 1 fc1 wave. Waves 0-1: independent single-wave
// LSTM tiles (latency-bound, LDS-private, no barriers). Waves 2-3: independent
// 64x64 fc1 tiles, NO LDS, NO barriers: A/W fragments loaded straight from
// global and hi/lo-split in registers; they fill lstm's stall cycles (m114).
#define TILE_LDS 10752
__global__ __launch_bounds__(256, 2) void fused_kernel(
    const unsigned short* __restrict__ xph, const unsigned short* __restrict__ xpl,
    const float* __restrict__ pw, const float* __restrict__ dw, const float* __restrict__ db,
    float* __restrict__ eo,
    const float* __restrict__ x, const float* __restrict__ W,
    const float* __restrict__ bias, float* __restrict__ C)
{
    __shared__ __align__(16) char smem[2 * TILE_LDS];

    const int w = threadIdx.x >> 6;
    const int l = threadIdx.x & 63;
    const int q = l >> 4, s = l & 15;

    if (w < 2) {
        // ================= LSTM path: wave w handles tile blockIdx*2+w =================
        const int tile = blockIdx.x * 2 + w;
        const int e = tile >> 6;
        const int c = tile & 63;
        const int b0 = c * 16;

        char* base = smem + w * TILE_LDS;
        short* h1h = (short*)base;          // 640 shorts each
        short* h1l = h1h + 640;
        short* h2h = h1l + 640;
        short* h2l = h2h + 640;
        float* zb  = (float*)(base + 5120); // 16*84 floats (shared by both layers)

        {   // zero h state
            int* hz = (int*)base;
            for (int i = l; i < 1280; i += 64) hz[i] = 0;
        }

        const float* Wm = pw + (size_t)e * PWE;
        bf16x8 K1h[5], K1l[5], R1h[5], R1l[5], K2h[5], K2l[5], R2h[5], R2l[5];
#pragma unroll
        for (int n = 0; n < 5; ++n) {
#pragma unroll
            for (int j = 0; j < 8; ++j) {
                int k = q * 8 + j;
                int cc = n * 16 + s;
                float wv_;
                unsigned short hi; float hf;
                wv_ = Wm[k * 80 + cc];
                hi = bf16_rne(wv_); hf = bf16_to_f(hi);
                K1h[n][j] = (short)hi; K1l[n][j] = (short)bf16_rne(wv_ - hf);
                wv_ = (k < Hh) ? Wm[2560 + k * 80 + cc] : 0.f;
                hi = bf16_rne(wv_); hf = bf16_to_f(hi);
                R1h[n][j] = (short)hi; R1l[n][j] = (short)bf16_rne(wv_ - hf);
                wv_ = (k < Hh) ? Wm[4160 + k * 80 + cc] : 0.f;
                hi = bf16_rne(wv_); hf = bf16_to_f(hi);
                K2h[n][j] = (short)hi; K2l[n][j] = (short)bf16_rne(wv_ - hf);
                wv_ = (k < Hh) ? Wm[5760 + k * 80 + cc] : 0.f;
                hi = bf16_rne(wv_); hf = bf16_to_f(hi);
                R2h[n][j] = (short)hi; R2l[n][j] = (short)bf16_rne(wv_ - hf);
            }
        }
        float bv1[5], bv2[5], dwr[5];
#pragma unroll
        for (int n = 0; n < 5; ++n) {
            bv1[n] = Wm[7360 + n * 16 + s];
            bv2[n] = Wm[7440 + n * 16 + s];
        }
#pragma unroll
        for (int i = 0; i < 5; ++i) dwr[i] = dw[e * Hh + 4 * i + q];

        float c1[5] = {0, 0, 0, 0, 0}, c2[5] = {0, 0, 0, 0, 0};
        float h2reg[5] = {0, 0, 0, 0, 0};

        const unsigned short* xbh = xph + (size_t)c * 65536 + l * 8;
        const unsigned short* xbl = xpl + (size_t)c * 65536 + l * 8;
        bf16x8 xch = *(const bf16x8*)xbh;
        bf16x8 xcl = *(const bf16x8*)xbl;

#pragma unroll 1
        for (int t = 0; t < Tt; ++t) {
            bf16x8 xnh = xch, xnl = xcl;
            if (t < Tt - 1) {       // prefetch t+1 (overlaps this step's compute)
                xnh = *(const bf16x8*)(xbh + (t + 1) * 512);
                xnl = *(const bf16x8*)(xbl + (t + 1) * 512);
            }
            bf16x8 H1a = *(bf16x8*)&h1h[s * 40 + q * 8];
            bf16x8 H1b = *(bf16x8*)&h1l[s * 40 + q * 8];
            bf16x8 H2a = *(bf16x8*)&h2h[s * 40 + q * 8];
            bf16x8 H2b = *(bf16x8*)&h2l[s * 40 + q * 8];

            f32x4 a1[5];
#pragma unroll
            for (int n = 0; n < 5; ++n) {
                f32x4 acc = {bv1[n], bv1[n], bv1[n], bv1[n]};
                acc = MFMA16(xch, K1h[n], acc);
                acc = MFMA16(xch, K1l[n], acc);
                acc = MFMA16(xcl, K1h[n], acc);
                acc = MFMA16(H1a, R1h[n], acc);
                acc = MFMA16(H1a, R1l[n], acc);
                acc = MFMA16(H1b, R1h[n], acc);
                a1[n] = acc;
            }
#pragma unroll
            for (int n = 0; n < 5; ++n)
#pragma unroll
                for (int r = 0; r < 4; ++r)
                    zb[(4 * q + r) * 84 + n * 16 + s] = a1[n][r];

#pragma unroll
            for (int i = 0; i < 5; ++i) {
                int u = 4 * i + q;
                f32x4 zz = *(f32x4*)&zb[s * 84 + 4 * u];
                float iv = sigmoidf_(zz[0]);
                float fv = sigmoidf_(zz[1]);
                float gv = fmaxf(zz[2], 0.f);
                float ov = sigmoidf_(zz[3]);
                c1[i] = fv * c1[i] + iv * gv;
                float h = ov * fmaxf(c1[i], 0.f);
                unsigned short hi = bf16_rne(h);
                h1h[s * 40 + u] = (short)hi;
                h1l[s * 40 + u] = (short)bf16_rne(h - bf16_to_f(hi));
            }

            bf16x8 H1c = *(bf16x8*)&h1h[s * 40 + q * 8];
            bf16x8 H1d = *(bf16x8*)&h1l[s * 40 + q * 8];
            f32x4 a2[5];
#pragma unroll
            for (int n = 0; n < 5; ++n) {
                f32x4 acc = {bv2[n], bv2[n], bv2[n], bv2[n]};
                acc = MFMA16(H1c, K2h[n], acc);
                acc = MFMA16(H1c, K2l[n], acc);
                acc = MFMA16(H1d, K2h[n], acc);
                acc = MFMA16(H2a, R2h[n], acc);
                acc = MFMA16(H2a, R2l[n], acc);
                acc = MFMA16(H2b, R2h[n], acc);
                a2[n] = acc;
            }
#pragma unroll
            for (int n = 0; n < 5; ++n)
#pragma unroll
                for (int r = 0; r < 4; ++r)
                    zb[(4 * q + r) * 84 + n * 16 + s] = a2[n][r];

#pragma unroll
            for (int i = 0; i < 5; ++i) {
                int u = 4 * i + q;
                f32x4 zz = *(f32x4*)&zb[s * 84 + 4 * u];
                float iv = sigmoidf_(zz[0]);
                float fv = sigmoidf_(zz[1]);
                float gv = fmaxf(zz[2], 0.f);
                float ov = sigmoidf_(zz[3]);
                c2[i] = fv * c2[i] + iv * gv;
                float h = ov * fmaxf(c2[i], 0.f);
                h2reg[i] = h;
                unsigned short hi = bf16_rne(h);
                h2h[s * 40 + u] = (short)hi;
                h2l[s * 40 + u] = (short)bf16_rne(h - bf16_to_f(hi));
            }
            xch = xnh; xcl = xnl;
        }

        float p = 0.f;
#pragma unroll
        for (int i = 0; i < 5; ++i) p += h2reg[i] * dwr[i];
        p += __shfl_xor(p, 16);
        p += __shfl_xor(p, 32);
        if (q == 0) eo[(size_t)e * Bsz + b0 + s] = db[e] + p;

    } else {
        // ================= fc1 path: one 64x64 tile per wave, LDS-free =================
        const int fid = blockIdx.x * 2 + (w - 2);
        const int m0 = (fid >> 6) * 64;
        const int n0 = (fid & 63) * 64;

        f32x4 acc[4][4];
#pragma unroll
        for (int mt = 0; mt < 4; ++mt)
#pragma unroll
            for (int nt = 0; nt < 4; ++nt) acc[mt][nt] = (f32x4){0.f, 0.f, 0.f, 0.f};

        // per-lane base pointers
        const float* Arow[4];
#pragma unroll
        for (int mt = 0; mt < 4; ++mt)
            Arow[mt] = x + (size_t)(m0 + mt * 16 + s) * Dd + q * 8;
        const float* Wbase = W + (size_t)(q * 8) * Dd + n0 + s;

#pragma unroll 1
        for (int k0 = 0; k0 < Dd; k0 += 32) {
            // ---- load A frags (8 consecutive floats per mt)
            float av[4][8];
#pragma unroll
            for (int mt = 0; mt < 4; ++mt) {
                *(float4*)&av[mt][0] = *(const float4*)(Arow[mt] + k0);
                *(float4*)&av[mt][4] = *(const float4*)(Arow[mt] + k0 + 4);
            }
            // ---- load W frags (gather, coalesced across s-lanes)
            float wv[4][8];
#pragma unroll
            for (int j = 0; j < 8; ++j) {
                const float* wr = Wbase + (size_t)(k0 + j) * Dd;
#pragma unroll
                for (int nt = 0; nt < 4; ++nt) wv[nt][j] = wr[nt * 16];
            }
            // ---- split to hi/lo bf16 frags
            bf16x8 Afh[4], Afl[4], Wfh[4], Wfl[4];
#pragma unroll
            for (int mt = 0; mt < 4; ++mt) split8(av[mt], Afh[mt], Afl[mt]);
#pragma unroll
            for (int nt = 0; nt < 4; ++nt) split8(wv[nt], Wfh[nt], Wfl[nt]);
            // ---- 48 MFMA
#pragma unroll
            for (int mt = 0; mt < 4; ++mt)
#pragma unroll
                for (int nt = 0; nt < 4; ++nt) {
                    f32x4 a = acc[mt][nt];
                    a = MFMA16(Afl[mt], Wfh[nt], a);
                    a = MFMA16(Afh[mt], Wfl[nt], a);
                    a = MFMA16(Afh[mt], Wfh[nt], a);
                    acc[mt][nt] = a;
                }
        }

        // epilogue: +bias, relu, store (C rows = 4q+r, cols = s within each 16x16 frag)
#pragma unroll
        for (int nt = 0; nt < 4; ++nt) {
            float bv = bias[n0 + nt * 16 + s];
#pragma unroll
            for (int mt = 0; mt < 4; ++mt)
#pragma unroll
                for (int r = 0; r < 4; ++r) {
                    int m = m0 + mt * 16 + q * 4 + r;
                    C[(size_t)m * Dd + n0 + nt * 16 + s] = fmaxf(acc[mt][nt][r] + bv, 0.f);
                }
        }
    }
}

// ---------------------------------------------------------------- gate: softmax(g @ gate_w + gb) + combine
__global__ __launch_bounds__(256) void gate_kernel(const float* __restrict__ g,
                                                   const float* __restrict__ gw,
                                                   const float* __restrict__ gb,
                                                   const float* __restrict__ eo,
                                                   float* __restrict__ out)
{
    int b = blockIdx.x;
    int tid = threadIdx.x;
    int lane = tid & 63;
    int wv = tid >> 6;

    float acc[16];
#pragma unroll
    for (int j = 0; j < 16; ++j) acc[j] = 0.f;

    const float* grow = g + (size_t)b * Dd;
#pragma unroll
    for (int it = 0; it < Dd / 256; ++it) {
        int d = tid + it * 256;
        float gv = grow[d];
        const float4* wr = (const float4*)(gw + (size_t)d * 16);
        float4 w0 = wr[0], w1 = wr[1], w2 = wr[2], w3 = wr[3];
        acc[0] += gv * w0.x;  acc[1] += gv * w0.y;  acc[2] += gv * w0.z;  acc[3] += gv * w0.w;
        acc[4] += gv * w1.x;  acc[5] += gv * w1.y;  acc[6] += gv * w1.z;  acc[7] += gv * w1.w;
        acc[8] += gv * w2.x;  acc[9] += gv * w2.y;  acc[10] += gv * w2.z; acc[11] += gv * w2.w;
        acc[12] += gv * w3.x; acc[13] += gv * w3.y; acc[14] += gv * w3.z; acc[15] += gv * w3.w;
    }

    __shared__ float red[64];
    __shared__ float logits[16];
#pragma unroll
    for (int j = 0; j < 16; ++j) {
        float v = acc[j];
#pragma unroll
        for (int m = 32; m >= 1; m >>= 1) v += __shfl_xor(v, m);
        if (lane == 0) red[wv * 16 + j] = v;
    }
    __syncthreads();
    if (tid < 16) {
        logits[tid] = gb[tid] + red[tid] + red[16 + tid] + red[32 + tid] + red[48 + tid];
    }
    __syncthreads();
    if (tid == 0) {
        float m = logits[0];
#pragma unroll
        for (int j = 1; j < 16; ++j) m = fmaxf(m, logits[j]);
        float ex[16], ssum = 0.f;
#pragma unroll
        for (int j = 0; j < 16; ++j) { ex[j] = __expf(logits[j] - m); ssum += ex[j]; }
        float inv = 1.f / ssum;
        float o = 0.f;
#pragma unroll
        for (int j = 0; j < 16; ++j) o += ex[j] * inv * eo[(size_t)j * Bsz + b];
        out[b] = o;
    }
}

// ----------------------------------------------------------------
extern "C" void kernel_launch(void* const* d_in, const int* in_sizes, int n_in,
                              void* d_out, int out_size, void* d_ws, size_t ws_size,
                              hipStream_t stream)
{
    const float* x     = (const float*)d_in[0];
    const float* gamma = (const float*)d_in[1];
    const float* beta  = (const float*)d_in[2];
    const float* mean  = (const float*)d_in[3];
    const float* var   = (const float*)d_in[4];
    const float* k1    = (const float*)d_in[5];
    const float* r1    = (const float*)d_in[6];
    const float* b1    = (const float*)d_in[7];
    const float* k2    = (const float*)d_in[8];
    const float* r2    = (const float*)d_in[9];
    const float* b2    = (const float*)d_in[10];
    const float* dw    = (const float*)d_in[11];
    const float* db    = (const float*)d_in[12];
    const float* fc1w  = (const float*)d_in[13];
    const float* fc1b  = (const float*)d_in[14];
    const float* gw    = (const float*)d_in[15];
    const float* gb    = (const float*)d_in[16];
    float* out = (float*)d_out;

    // workspace: 33.1 MB (<= previously-proven 34.2 MB footprint)
    float* g = (float*)d_ws;                                        // 4,194,304 f (16 MB)
    unsigned short* xph = (unsigned short*)(g + (size_t)Bsz * Dd);  // 4,194,304 us (8 MB)
    unsigned short* xpl = xph + (size_t)4194304;                    // 8 MB
    float* pw  = (float*)(xpl + (size_t)4194304);                   // 120,320 f
    float* eo  = pw + (size_t)Ee * PWE;                             // 16,384 f

    xpack_kernel<<<2048, 256, 0, stream>>>(x, gamma, beta, mean, var, xph, xpl);
    repack2_kernel<<<(Ee * PWE + 255) / 256, 256, 0, stream>>>(k1, r1, b1, k2, r2, b2, pw);
    fused_kernel<<<512, 256, 0, stream>>>(xph, xpl, pw, dw, db, eo, x, fc1w, fc1b, g);
    gate_kernel<<<Bsz, 256, 0, stream>>>(g, gw, gb, eo, out);
}